// Round 10
// baseline (652.490 us; speedup 1.0000x reference)
//
#include <hip/hip_runtime.h>

typedef unsigned short u16;
typedef unsigned int u32;
typedef float f32x4 __attribute__((ext_vector_type(4)));
typedef __bf16 bf16x8 __attribute__((ext_vector_type(8)));

#define F 256
#define T_OUT 8
#define N_MONO 150000
#define N_CLEAV 100000
#define N_FRAG 80000
#define N_FRAG_PAD 80128     // 626 * 128
#define N_OUT 40000
#define M_CLEAV_PAD 100352   // 448 * 224

static __device__ __forceinline__ u16 f2bf(float f) {
  u32 u = __float_as_uint(f);
  u32 r = (u + 0x7FFFu + ((u >> 16) & 1u)) >> 16;
  return (u16)r;
}
static __device__ __forceinline__ float bf2f(u16 b) {
  return __uint_as_float(((u32)b) << 16);
}
static __device__ __forceinline__ float sigmoidf(float x) {
  return __frcp_rn(1.0f + __expf(-x));
}
static __device__ __forceinline__ float fast_tanh(float x) {
  return 1.0f - 2.0f * __frcp_rn(__expf(2.0f * x) + 1.0f);
}
static __device__ __forceinline__ void async_copy16(const u16* g, const u16* l) {
  __builtin_amdgcn_global_load_lds(
      (const __attribute__((address_space(1))) u32*)g,
      (__attribute__((address_space(3))) u32*)l,
      16, 0, 0);
}

// ---------------- K0a: weight cast + bias sum ----------------
__global__ __launch_bounds__(256) void prep_kernel(
    const float* __restrict__ Wih, const float* __restrict__ Whh,
    const float* __restrict__ bih, const float* __restrict__ bhh,
    u16* __restrict__ Wihb, u16* __restrict__ Whhb, float* __restrict__ bias) {
  int i = blockIdx.x * 256 + threadIdx.x;
  if (i < 1024 * 512) Wihb[i] = f2bf(Wih[i]);
  if (i < 1024 * 256) Whhb[i] = f2bf(Whh[i]);
  if (i < 1024) bias[i] = bih[i] + bhh[i];
}

// ------- K0b: feature bf16 copy + per-mono gate logits --------
__global__ __launch_bounds__(256) void feat_prep(
    const float* __restrict__ feat, const float* __restrict__ WgL,
    const float* __restrict__ WgR, u16* __restrict__ featb,
    float* __restrict__ glog) {
  int wave = threadIdx.x >> 6, lane = threadIdx.x & 63;
  int n = blockIdx.x * 4 + wave;
  if (n >= N_MONO) return;
  float4 x = *(const float4*)(feat + (size_t)n * F + lane * 4);
  u32 lo = (u32)f2bf(x.x) | ((u32)f2bf(x.y) << 16);
  u32 hi = (u32)f2bf(x.z) | ((u32)f2bf(x.w) << 16);
  *(uint2*)(featb + (size_t)n * F + lane * 4) = make_uint2(lo, hi);
  float4 wl = *(const float4*)(WgL + lane * 4);
  float4 wr = *(const float4*)(WgR + lane * 4);
  float pl = x.x * wl.x + x.y * wl.y + x.z * wl.z + x.w * wl.w;
  float pr = x.x * wr.x + x.y * wr.y + x.z * wr.z + x.w * wr.w;
#pragma unroll
  for (int off = 32; off; off >>= 1) {
    pl += __shfl_xor(pl, off);
    pr += __shfl_xor(pr, off);
  }
  if (lane == 0) {
    glog[n * 2] = pl;
    glog[n * 2 + 1] = pr;
  }
}

// ---------------- K1: attention pulls -> cleav [N_CLEAV, 512] bf16 --------
// TWO cleavages per wave (R9 verified): 32 loads in flight before compute.
__global__ __launch_bounds__(256) void attn_pull2(
    const u16* __restrict__ featb, const float* __restrict__ glog,
    const int* __restrict__ lostS, const int* __restrict__ retS,
    u16* __restrict__ cleav) {
  int wave = threadIdx.x >> 6, lane = threadIdx.x & 63;
  int n0 = blockIdx.x * 8 + wave * 2;
  if (n0 >= N_CLEAV) return;
  int r[2][2][4];
#pragma unroll
  for (int c = 0; c < 2; ++c) {
    int4 rl = *(const int4*)(lostS + (n0 + c) * 4);
    int4 rr = *(const int4*)(retS + (n0 + c) * 4);
    r[c][0][0] = rl.x; r[c][0][1] = rl.y; r[c][0][2] = rl.z; r[c][0][3] = rl.w;
    r[c][1][0] = rr.x; r[c][1][1] = rr.y; r[c][1][2] = rr.z; r[c][1][3] = rr.w;
  }
  ushort4 x4[2][2][4];
  float lg[2][2][4];
#pragma unroll
  for (int c = 0; c < 2; ++c)
#pragma unroll
    for (int sg = 0; sg < 2; ++sg)
#pragma unroll
      for (int d = 0; d < 4; ++d) {
        x4[c][sg][d] = *(const ushort4*)(featb + (size_t)r[c][sg][d] * F + lane * 4);
        lg[c][sg][d] = glog[r[c][sg][d] * 2 + sg];
      }
#pragma unroll
  for (int c = 0; c < 2; ++c)
#pragma unroll
    for (int sg = 0; sg < 2; ++sg) {
      float l0 = lg[c][sg][0], l1 = lg[c][sg][1];
      float l2 = lg[c][sg][2], l3 = lg[c][sg][3];
      float mx = fmaxf(fmaxf(l0, l1), fmaxf(l2, l3));
      float e0 = __expf(l0 - mx), e1 = __expf(l1 - mx);
      float e2 = __expf(l2 - mx), e3 = __expf(l3 - mx);
      float inv = __frcp_rn(e0 + e1 + e2 + e3);
      float a[4] = {e0 * inv, e1 * inv, e2 * inv, e3 * inv};
      float acc[4] = {0.f, 0.f, 0.f, 0.f};
#pragma unroll
      for (int d = 0; d < 4; ++d) {
        const u16* xp = (const u16*)&x4[c][sg][d];
#pragma unroll
        for (int k = 0; k < 4; k++) acc[k] += a[d] * bf2f(xp[k]);
      }
      u32 lo = (u32)f2bf(acc[0]) | ((u32)f2bf(acc[1]) << 16);
      u32 hi = (u32)f2bf(acc[2]) | ((u32)f2bf(acc[3]) << 16);
      *(uint2*)(cleav + (size_t)(n0 + c) * 512 + sg * 256 + lane * 4) =
          make_uint2(lo, hi);
    }
}

// ---------------- GEMM-1: P = cleav @ Wih^T + bias, PERSISTENT ------------
// 256 blocks = 1/CU (LDS-forced).  Each block: fixed nstrip (B panel stays
// L2-hot), 7 consecutive mstrips on its own XCD.  The verified 4-phase
// double-buffered schedule runs over ONE concatenated stream of 56 K-tiles:
// stageA(g+1) in phases 1-2, stageB(g+2) in phases 3-4, boundary vmcnt(4).
// A-staging switches source rows at tile boundaries; the epilogue (C-write
// + acc reset) executes after every 8th boundary barrier while the next
// tile's loads remain in flight -> prologue/drain serialization of the old
// 7-round dispatch disappears.  Steady-state vmcnt invariant is unchanged:
// at each boundary all but the newest 4 (B(g+2)) loads have landed.
__global__ __launch_bounds__(512, 2) void gemm224(
    const u16* __restrict__ A, const u16* __restrict__ Bw,
    u16* __restrict__ C, const float* __restrict__ bias) {
  constexpr int K = 512, BM = 224;
  constexpr int AREG = BM * 64;
  constexpr int BSZ = AREG + 16384;
  constexpr int WMH = BM / 2;
  constexpr int IB = BM / 32;            // 7
  constexpr int IB_HI = IB - 4;          // 3
  constexpr int NT = 7;                  // tiles per block
  constexpr int G = NT * 8;              // global K-tile stream length
  __shared__ u16 sh[2][BSZ];
  const int b = blockIdx.x;              // 0..255
  const int xcd = b & 7;
  const int s = b >> 3;                  // 0..31
  const int nstrip = s & 3;
  const int mgrp = s >> 2;               // 0..7
  const int mstrip0 = xcd * 56 + mgrp * 7;
  const int n0 = nstrip * 256;

  const int tid = threadIdx.x;
  const int lane = tid & 63;
  const int wave = tid >> 6;
  const int quad = lane >> 4;
  const int l16 = lane & 15;
  const int s7 = l16 & 7;
  const int wm2 = wave >> 2;
  const int wn4 = wave & 3;

  const int arow = (wm2 * WMH + l16) * 64;
  const int brow = AREG + (wn4 * 64 + l16) * 64;
  const int coff0 = (quad ^ s7) * 8;
  const int coff1 = ((4 + quad) ^ s7) * 8;

  int sr[4], sw[4], dwv[4];
#pragma unroll
  for (int r = 0; r < 4; r++) {
    int c = r * 512 + tid;
    sr[r] = c >> 3;
    sw[r] = ((c & 7) ^ ((c >> 3) & 7)) * 8;
    dwv[r] = (r * 512 + (tid & ~63)) * 8;
  }
  const u16* Bbase = Bw + (size_t)n0 * K;

  auto stageA = [&](int buf, int g, int h) {
    const u16* Ab = A + (size_t)(mstrip0 + (g >> 3)) * BM * K;
    const int kt = g & 7;
#pragma unroll
    for (int rr = 0; rr < 2; rr++) {
      int r = 2 * h + rr;
      if (r * 512 + tid < BM * 8)
        async_copy16(Ab + (size_t)sr[r] * K + kt * 64 + sw[r], &sh[buf][dwv[r]]);
    }
  };
  auto stageB = [&](int buf, int g, int h) {
    const int kt = g & 7;
#pragma unroll
    for (int rr = 0; rr < 2; rr++) {
      int r = 2 * h + rr;
      async_copy16(Bbase + (size_t)sr[r] * K + kt * 64 + sw[r], &sh[buf][AREG + dwv[r]]);
    }
  };

  float badd[4];
#pragma unroll
  for (int j = 0; j < 4; j++)
    badd[j] = bias[n0 + wn4 * 64 + j * 16 + l16];

  f32x4 acc[IB][4];
#pragma unroll
  for (int i = 0; i < IB; i++)
#pragma unroll
    for (int j = 0; j < 4; j++) acc[i][j] = (f32x4){0.f, 0.f, 0.f, 0.f};

  stageA(0, 0, 0); stageA(0, 0, 1); stageB(0, 0, 0); stageB(0, 0, 1);
  stageB(1, 1, 0); stageB(1, 1, 1);
  __builtin_amdgcn_s_waitcnt(0xF74);
  __builtin_amdgcn_s_barrier();

  bf16x8 a[4][2], b0[2][2], b1[2][2];
  for (int g = 0; g < G; ++g) {
    const int bsel = g & 1;
    const u16* S = &sh[bsel][0];

    // ---- phase 1: i 0-3, j 0-1; stage A(g+1) half0.
#pragma unroll
    for (int i = 0; i < 4; i++) {
      a[i][0] = *(const bf16x8*)&S[arow + i * 1024 + coff0];
      a[i][1] = *(const bf16x8*)&S[arow + i * 1024 + coff1];
    }
#pragma unroll
    for (int j = 0; j < 2; j++) {
      b0[j][0] = *(const bf16x8*)&S[brow + j * 1024 + coff0];
      b0[j][1] = *(const bf16x8*)&S[brow + j * 1024 + coff1];
    }
    if (g + 1 < G) stageA(bsel ^ 1, g + 1, 0);
    __builtin_amdgcn_s_waitcnt(0xC87F);
    __builtin_amdgcn_s_barrier();
    __builtin_amdgcn_s_waitcnt(0xC07F);
    __builtin_amdgcn_sched_barrier(0);
    __builtin_amdgcn_s_setprio(1);
#pragma unroll
    for (int i = 0; i < 4; i++)
#pragma unroll
      for (int j = 0; j < 2; j++) {
        acc[i][j] = __builtin_amdgcn_mfma_f32_16x16x32_bf16(a[i][0], b0[j][0], acc[i][j], 0, 0, 0);
        acc[i][j] = __builtin_amdgcn_mfma_f32_16x16x32_bf16(a[i][1], b0[j][1], acc[i][j], 0, 0, 0);
      }
    __builtin_amdgcn_s_setprio(0);
    __builtin_amdgcn_s_barrier();

    // ---- phase 2: i 0-3, j 2-3; stage A(g+1) half1.
#pragma unroll
    for (int j = 0; j < 2; j++) {
      b1[j][0] = *(const bf16x8*)&S[brow + (2 + j) * 1024 + coff0];
      b1[j][1] = *(const bf16x8*)&S[brow + (2 + j) * 1024 + coff1];
    }
    if (g + 1 < G) stageA(bsel ^ 1, g + 1, 1);
    __builtin_amdgcn_s_barrier();
    __builtin_amdgcn_s_waitcnt(0xC07F);
    __builtin_amdgcn_sched_barrier(0);
    __builtin_amdgcn_s_setprio(1);
#pragma unroll
    for (int i = 0; i < 4; i++)
#pragma unroll
      for (int j = 0; j < 2; j++) {
        acc[i][2 + j] = __builtin_amdgcn_mfma_f32_16x16x32_bf16(a[i][0], b1[j][0], acc[i][2 + j], 0, 0, 0);
        acc[i][2 + j] = __builtin_amdgcn_mfma_f32_16x16x32_bf16(a[i][1], b1[j][1], acc[i][2 + j], 0, 0, 0);
      }
    __builtin_amdgcn_s_setprio(0);
    __builtin_amdgcn_s_barrier();

    // ---- phase 3: i 4-6, j 0-1; stage B(g+2) half0.
#pragma unroll
    for (int i = 0; i < IB_HI; i++) {
      a[i][0] = *(const bf16x8*)&S[arow + (4 + i) * 1024 + coff0];
      a[i][1] = *(const bf16x8*)&S[arow + (4 + i) * 1024 + coff1];
    }
    if (g + 2 < G) stageB(bsel, g + 2, 0);
    __builtin_amdgcn_s_barrier();
    __builtin_amdgcn_s_waitcnt(0xC07F);
    __builtin_amdgcn_sched_barrier(0);
    __builtin_amdgcn_s_setprio(1);
#pragma unroll
    for (int i = 0; i < IB_HI; i++)
#pragma unroll
      for (int j = 0; j < 2; j++) {
        acc[4 + i][j] = __builtin_amdgcn_mfma_f32_16x16x32_bf16(a[i][0], b0[j][0], acc[4 + i][j], 0, 0, 0);
        acc[4 + i][j] = __builtin_amdgcn_mfma_f32_16x16x32_bf16(a[i][1], b0[j][1], acc[4 + i][j], 0, 0, 0);
      }
    __builtin_amdgcn_s_setprio(0);
    __builtin_amdgcn_s_barrier();

    // ---- phase 4: i 4-6, j 2-3; stage B(g+2) half1; boundary vmcnt.
    if (g + 2 < G) stageB(bsel, g + 2, 1);
    __builtin_amdgcn_s_barrier();
    __builtin_amdgcn_s_setprio(1);
#pragma unroll
    for (int i = 0; i < IB_HI; i++)
#pragma unroll
      for (int j = 0; j < 2; j++) {
        acc[4 + i][2 + j] = __builtin_amdgcn_mfma_f32_16x16x32_bf16(a[i][0], b1[j][0], acc[4 + i][2 + j], 0, 0, 0);
        acc[4 + i][2 + j] = __builtin_amdgcn_mfma_f32_16x16x32_bf16(a[i][1], b1[j][1], acc[4 + i][2 + j], 0, 0, 0);
      }
    __builtin_amdgcn_s_setprio(0);
    if (g + 2 < G) __builtin_amdgcn_s_waitcnt(0xF74);
    else           __builtin_amdgcn_s_waitcnt(0xF70);
    __builtin_amdgcn_s_barrier();

    // ---- tile boundary: epilogue while next tile's loads are in flight.
    if ((g & 7) == 7) {
      const int m0 = (mstrip0 + (g >> 3)) * BM;
#pragma unroll
      for (int i = 0; i < IB; i++) {
        const int mrow = m0 + wm2 * WMH + i * 16 + quad * 4;
#pragma unroll
        for (int j = 0; j < 4; j++) {
          const int n = n0 + wn4 * 64 + j * 16 + l16;
#pragma unroll
          for (int r = 0; r < 4; r++)
            C[(size_t)(mrow + r) * 1024 + n] = f2bf(acc[i][j][r] + badd[j]);
        }
      }
#pragma unroll
      for (int i = 0; i < IB; i++)
#pragma unroll
        for (int j = 0; j < 4; j++) acc[i][j] = (f32x4){0.f, 0.f, 0.f, 0.f};
    }
  }
}

// ---------------- K3: LSTM step 1, TWO fragments per wave -----------------
__global__ __launch_bounds__(256) void lstm_step1(
    const u16* __restrict__ P, const int* __restrict__ join,
    u16* __restrict__ h1, u16* __restrict__ c1) {
  int wave = threadIdx.x >> 6, lane = threadIdx.x & 63;
  int m0 = blockIdx.x * 8 + wave * 2;
  if (m0 >= N_FRAG_PAD) return;
#pragma unroll
  for (int c = 0; c < 2; ++c) {
    int m = m0 + c;
    if (m >= N_FRAG) {
      if (m < N_FRAG_PAD) {
        *(ushort4*)(h1 + (size_t)m * 256 + lane * 4) = make_ushort4(0, 0, 0, 0);
        *(ushort4*)(c1 + (size_t)m * 256 + lane * 4) = make_ushort4(0, 0, 0, 0);
      }
    }
  }
  if (m0 + 1 >= N_FRAG) return;   // tail handled above (wave-uniform)
  int j0a = join[2 * m0];
  int j0b = join[2 * (m0 + 1)];
  const u16* rowa = P + (size_t)j0a * 1024 + lane * 4;
  const u16* rowb = P + (size_t)j0b * 1024 + lane * 4;
  ushort4 iva = *(const ushort4*)(rowa);
  ushort4 gva = *(const ushort4*)(rowa + 512);
  ushort4 ova = *(const ushort4*)(rowa + 768);
  ushort4 ivb = *(const ushort4*)(rowb);
  ushort4 gvb = *(const ushort4*)(rowb + 512);
  ushort4 ovb = *(const ushort4*)(rowb + 768);
#pragma unroll
  for (int c = 0; c < 2; ++c) {
    const u16* ivp = (const u16*)(c ? &ivb : &iva);
    const u16* gvp = (const u16*)(c ? &gvb : &gva);
    const u16* ovp = (const u16*)(c ? &ovb : &ova);
    ushort4 h4, c4;
    u16* h4p = (u16*)&h4;
    u16* c4p = (u16*)&c4;
#pragma unroll
    for (int k = 0; k < 4; k++) {
      float cc = sigmoidf(bf2f(ivp[k])) * fast_tanh(bf2f(gvp[k]));
      float hv = sigmoidf(bf2f(ovp[k])) * fast_tanh(cc);
      h4p[k] = f2bf(hv);
      c4p[k] = f2bf(cc);
    }
    *(ushort4*)(h1 + (size_t)(m0 + c) * 256 + lane * 4) = h4;
    *(ushort4*)(c1 + (size_t)(m0 + c) * 256 + lane * 4) = c4;
  }
}

// ------- G2 fused: gates2 = h1 @ Whh^T (+P[j1], +c1) -> h2  ---------------
// 128x128 tile, BK=32, triple-buffered, 3 blocks/CU, XCD-colocated (R8).
__global__ __launch_bounds__(256, 3) void g2fuse(
    const u16* __restrict__ h1A, const u16* __restrict__ Whhb,
    const u16* __restrict__ P, const int* __restrict__ join,
    const u16* __restrict__ c1in, u16* __restrict__ h2s) {
  constexpr int K = 256;
  __shared__ u16 sh[6][128 * 32];   // A bufs 0-2, B bufs 3-5 (48 KiB)
  const int b = blockIdx.x;
  const int xcd = b & 7;
  const int k = b >> 3;             // 0..631
  const int nstrip = k & 7;
  const int mstrip = (k >> 3) * 8 + xcd;   // 0..631
  if (mstrip >= 626) return;
  const int m0 = mstrip * 128;

  const int tid = threadIdx.x;
  const int lane = tid & 63;
  const int wave = tid >> 6;
  const int quad = lane >> 4;
  const int l16 = lane & 15;
  const int wm = (wave & 1) * 64;
  const int wnq = wave >> 1;        // 0..1
  const int wn = wnq * 64;

  int srow[2], skoff[2], ldsoff[2], brow[2];
#pragma unroll
  for (int jj = 0; jj < 2; jj++) {
    int c = jj * 256 + tid;
    int row = c >> 2;
    srow[jj] = row;
    skoff[jj] = ((c & 3) ^ ((c >> 3) & 3)) * 8;
    ldsoff[jj] = (jj * 256 + (tid & ~63)) * 8;
    brow[jj] = ((row >> 4) & 3) * 256 + nstrip * 32 + ((row >> 6) << 4) + (row & 15);
  }
  const u16* Abase = h1A + (size_t)m0 * K;

  int jrow[8];
#pragma unroll
  for (int rd = 0; rd < 8; rd++) {
    int mm = m0 + rd * 16 + (tid >> 4);
    jrow[rd] = join[2 * (mm < N_FRAG ? mm : N_FRAG - 1) + 1];
  }

  auto stage = [&](int buf, int k0) {
#pragma unroll
    for (int jj = 0; jj < 2; jj++)
      async_copy16(Abase + (size_t)srow[jj] * K + k0 + skoff[jj], &sh[buf][ldsoff[jj]]);
#pragma unroll
    for (int jj = 0; jj < 2; jj++)
      async_copy16(Whhb + (size_t)brow[jj] * K + k0 + skoff[jj], &sh[3 + buf][ldsoff[jj]]);
  };

  f32x4 acc[4][4];
#pragma unroll
  for (int i = 0; i < 4; i++)
#pragma unroll
    for (int j = 0; j < 4; j++) acc[i][j] = (f32x4){0.f, 0.f, 0.f, 0.f};

  constexpr int nK = K / 32;        // 8
  stage(0, 0);
  stage(1, 32);
#pragma unroll
  for (int t = 0; t < nK; ++t) {
    if (t < nK - 1) __builtin_amdgcn_s_waitcnt(0xF74);  // vmcnt(4)
    else            __builtin_amdgcn_s_waitcnt(0xF70);  // vmcnt(0)
    __builtin_amdgcn_s_barrier();
    if (t + 2 < nK) stage((t + 2) % 3, (t + 2) * 32);
    const int buf = t % 3;
    bf16x8 af[4], bfr[4];
#pragma unroll
    for (int i = 0; i < 4; i++) {
      int m = wm + i * 16 + l16;
      int jp = quad ^ ((m >> 1) & 3);
      af[i] = *(const bf16x8*)&sh[buf][m * 32 + jp * 8];
    }
#pragma unroll
    for (int j = 0; j < 4; j++) {
      int n = wn + j * 16 + l16;
      int jp = quad ^ ((n >> 1) & 3);
      bfr[j] = *(const bf16x8*)&sh[3 + buf][n * 32 + jp * 8];
    }
#pragma unroll
    for (int i = 0; i < 4; i++)
#pragma unroll
      for (int j = 0; j < 4; j++)
        acc[i][j] = __builtin_amdgcn_mfma_f32_16x16x32_bf16(af[i], bfr[j], acc[i][j], 0, 0, 0);
  }

  // ---- fused LSTM step-2 epilogue ----
  __builtin_amdgcn_s_barrier();
  const int u_ = wnq * 16 + l16;
  u16 c1r[4][4];
#pragma unroll
  for (int i = 0; i < 4; i++)
#pragma unroll
    for (int r = 0; r < 4; r++) {
      int m = m0 + wm + i * 16 + quad * 4 + r;
      c1r[i][r] = c1in[(size_t)m * 256 + nstrip * 32 + u_];
    }
  u16* Pl = &sh[0][0];              // 32 KiB
  {
    const int g = (tid >> 2) & 3;
    const int chunk = tid & 3;
#pragma unroll
    for (int rd = 0; rd < 8; rd++) {
      const int mloc = rd * 16 + (tid >> 4);
      const int cphys = chunk ^ ((mloc >> 2) & 3);
      async_copy16(P + (size_t)jrow[rd] * 1024 + g * 256 + nstrip * 32 + cphys * 8,
                   &Pl[(size_t)(rd * 256 + (tid & ~63)) * 8]);
    }
  }
  __builtin_amdgcn_s_waitcnt(0xF70);
  __builtin_amdgcn_s_barrier();
  __builtin_amdgcn_sched_barrier(0);

#pragma unroll
  for (int i = 0; i < 4; i++) {
#pragma unroll
    for (int r = 0; r < 4; r++) {
      const int mloc = wm + i * 16 + quad * 4 + r;
      const int m = m0 + mloc;
      const int base = (mloc * 16 + ((u_ >> 3) ^ ((mloc >> 2) & 3))) * 8 + (u_ & 7);
      float gi = acc[i][0][r] + bf2f(Pl[base]);
      float gf = acc[i][1][r] + bf2f(Pl[base + 32]);
      float gg = acc[i][2][r] + bf2f(Pl[base + 64]);
      float go = acc[i][3][r] + bf2f(Pl[base + 96]);
      float c1v = bf2f(c1r[i][r]);
      float cv = sigmoidf(gf) * c1v + sigmoidf(gi) * fast_tanh(gg);
      float hv = sigmoidf(go) * fast_tanh(cv);
      h2s[(size_t)m * 256 + nstrip * 32 + u_] = f2bf(hv);
    }
  }
}

// ------- K5: attention over {h1,h2} + output head, TWO frags per wave -----
__global__ __launch_bounds__(256) void lstm_attn_out(
    const u16* __restrict__ h1, const u16* __restrict__ h2s,
    const float* __restrict__ Wg, const float* __restrict__ Wout,
    const float* __restrict__ bout, float* __restrict__ frag_out) {
  int wave = threadIdx.x >> 6, lane = threadIdx.x & 63;
  int m0 = blockIdx.x * 8 + wave * 2;
  if (m0 >= N_FRAG) return;
  const int nf = (m0 + 1 < N_FRAG) ? 2 : 1;
  ushort4 h1v[2], h2v[2];
#pragma unroll
  for (int c = 0; c < 2; ++c) {
    int m = m0 + (c < nf ? c : 0);
    h1v[c] = *(const ushort4*)(h1 + (size_t)m * 256 + lane * 4);
    h2v[c] = *(const ushort4*)(h2s + (size_t)m * 256 + lane * 4);
  }
  float4 wg = *(const float4*)(Wg + lane * 4);
  const float* wgp = (const float*)&wg;

  float p1[2], p2[2];
#pragma unroll
  for (int c = 0; c < 2; ++c) {
    const u16* h1p = (const u16*)&h1v[c];
    const u16* h2p = (const u16*)&h2v[c];
    float a = 0.f, b = 0.f;
#pragma unroll
    for (int k = 0; k < 4; k++) {
      a += bf2f(h1p[k]) * wgp[k];
      b += bf2f(h2p[k]) * wgp[k];
    }
    p1[c] = a; p2[c] = b;
  }
#pragma unroll
  for (int off = 32; off; off >>= 1)
#pragma unroll
    for (int c = 0; c < 2; ++c) {
      p1[c] += __shfl_xor(p1[c], off);
      p2[c] += __shfl_xor(p2[c], off);
    }

  float acc[2][8];
#pragma unroll
  for (int c = 0; c < 2; ++c) {
    float mx = fmaxf(p1[c], p2[c]);
    float e1 = __expf(p1[c] - mx), e2 = __expf(p2[c] - mx);
    float inv = __frcp_rn(e1 + e2);
    float a1 = e1 * inv, a2 = e2 * inv;
    const u16* h1p = (const u16*)&h1v[c];
    const u16* h2p = (const u16*)&h2v[c];
#pragma unroll
    for (int t = 0; t < 8; t++) acc[c][t] = 0.f;
#pragma unroll
    for (int k = 0; k < 4; k++) {
      float frag = a1 * bf2f(h1p[k]) + a2 * bf2f(h2p[k]);
      int h = lane * 4 + k;
      float4 w0 = *(const float4*)(Wout + h * 8);
      float4 w1 = *(const float4*)(Wout + h * 8 + 4);
      acc[c][0] += frag * w0.x; acc[c][1] += frag * w0.y;
      acc[c][2] += frag * w0.z; acc[c][3] += frag * w0.w;
      acc[c][4] += frag * w1.x; acc[c][5] += frag * w1.y;
      acc[c][6] += frag * w1.z; acc[c][7] += frag * w1.w;
    }
  }
#pragma unroll
  for (int off = 32; off; off >>= 1)
#pragma unroll
    for (int c = 0; c < 2; ++c)
#pragma unroll
      for (int t = 0; t < 8; t++) acc[c][t] += __shfl_xor(acc[c][t], off);
  if (lane == 0) {
#pragma unroll
    for (int c = 0; c < 2; ++c) {
      if (c >= nf) break;
      float4 o0, o1;
      o0.x = fmaxf(acc[c][0] + bout[0], 0.f);
      o0.y = fmaxf(acc[c][1] + bout[1], 0.f);
      o0.z = fmaxf(acc[c][2] + bout[2], 0.f);
      o0.w = fmaxf(acc[c][3] + bout[3], 0.f);
      o1.x = fmaxf(acc[c][4] + bout[4], 0.f);
      o1.y = fmaxf(acc[c][5] + bout[5], 0.f);
      o1.z = fmaxf(acc[c][6] + bout[6], 0.f);
      o1.w = fmaxf(acc[c][7] + bout[7], 0.f);
      *(float4*)(frag_out + (size_t)(m0 + c) * 8) = o0;
      *(float4*)(frag_out + (size_t)(m0 + c) * 8 + 4) = o1;
    }
  }
}

// ---------------- K6: combine scatter-sum ---------------------------------
__global__ __launch_bounds__(256) void scatter_sum(
    const float* __restrict__ frag_out, const int* __restrict__ comb,
    float* __restrict__ out) {
  int tid = blockIdx.x * 256 + threadIdx.x;
  if (tid >= N_OUT * 8) return;
  int n = tid >> 3, t = tid & 7;
  float s = 0.f;
#pragma unroll
  for (int d = 0; d < 4; d++) {
    int f = comb[n * 4 + d];
    s += frag_out[(size_t)f * 8 + t];
  }
  out[tid] = s;
}

extern "C" void kernel_launch(void* const* d_in, const int* in_sizes, int n_in,
                              void* d_out, int out_size, void* d_ws, size_t ws_size,
                              hipStream_t stream) {
  const float* feature = (const float*)d_in[0];
  const float* WgL = (const float*)d_in[1];
  const float* WgR = (const float*)d_in[2];
  const float* Wih = (const float*)d_in[3];
  const float* Whh = (const float*)d_in[4];
  const float* bih = (const float*)d_in[5];
  const float* bhh = (const float*)d_in[6];
  const float* Wgf = (const float*)d_in[7];
  const float* Wout = (const float*)d_in[8];
  const float* bout = (const float*)d_in[9];
  const int* lostS = (const int*)d_in[10];
  const int* retS = (const int*)d_in[11];
  const int* joinS = (const int*)d_in[12];
  const int* combS = (const int*)d_in[13];
  float* out = (float*)d_out;

  char* ws = (char*)d_ws;
  size_t off = 0;
  auto alloc = [&](size_t bytes) -> char* {
    char* p = ws + off;
    off = (off + bytes + 255) & ~(size_t)255;
    return p;
  };
  u16* Wihb = (u16*)alloc((size_t)1024 * 512 * 2);
  u16* Whhb = (u16*)alloc((size_t)1024 * 256 * 2);
  float* bias = (float*)alloc(1024 * 4);
  u16* P = (u16*)alloc((size_t)M_CLEAV_PAD * 1024 * 2);
  u16* h1 = (u16*)alloc((size_t)N_FRAG_PAD * 256 * 2);
  u16* c1 = (u16*)alloc((size_t)N_FRAG_PAD * 256 * 2);
  u16* h2s = (u16*)alloc((size_t)N_FRAG_PAD * 256 * 2);
  float* frag_out = (float*)alloc((size_t)N_FRAG * 8 * 4);
  u16* cleav = (u16*)alloc((size_t)M_CLEAV_PAD * 512 * 2);
  // featb (76.8 MB) + glog (1.2 MB) alias the P region: dead once
  // attn_pull2 completes, before GEMM-1 writes P (stream-ordered).
  u16* featb = P;
  float* glog = (float*)(P + (size_t)N_MONO * F);

  prep_kernel<<<2048, 256, 0, stream>>>(Wih, Whh, bih, bhh, Wihb, Whhb, bias);
  feat_prep<<<(N_MONO + 3) / 4, 256, 0, stream>>>(feature, WgL, WgR, featb, glog);
  attn_pull2<<<N_CLEAV / 8, 256, 0, stream>>>(featb, glog, lostS, retS, cleav);
  // GEMM-1 persistent: 256 blocks = 1/CU; block owns fixed nstrip + 7
  // consecutive mstrips on its XCD (448 mstrips x 4 nstrips total).
  gemm224<<<256, 512, 0, stream>>>(cleav, Wihb, P, bias);
  lstm_step1<<<N_FRAG_PAD / 8, 256, 0, stream>>>(P, joinS, h1, c1);
  // G2 fused: 632 virtual mstrips (79/XCD) x 8 nstrips, XCD-colocated
  g2fuse<<<632 * 8, 256, 0, stream>>>(h1, Whhb, P, joinS, c1, h2s);
  lstm_attn_out<<<(N_FRAG + 7) / 8, 256, 0, stream>>>(
      h1, h2s, Wgf, Wout, bout, frag_out);
  scatter_sum<<<(N_OUT * 8 + 255) / 256, 256, 0, stream>>>(frag_out, combS, out);
}

// Round 12
// 649.889 us; speedup vs baseline: 1.0040x; 1.0040x over previous
//
#include <hip/hip_runtime.h>

typedef unsigned short u16;
typedef unsigned int u32;
typedef float f32x4 __attribute__((ext_vector_type(4)));
typedef __bf16 bf16x8 __attribute__((ext_vector_type(8)));

#define F 256
#define T_OUT 8
#define N_MONO 150000
#define N_CLEAV 100000
#define N_FRAG 80000
#define N_FRAG_PAD 80128     // 626 * 128
#define N_OUT 40000
#define M_CLEAV_PAD 100352   // 448 * 224

static __device__ __forceinline__ u16 f2bf(float f) {
  u32 u = __float_as_uint(f);
  u32 r = (u + 0x7FFFu + ((u >> 16) & 1u)) >> 16;
  return (u16)r;
}
static __device__ __forceinline__ float bf2f(u16 b) {
  return __uint_as_float(((u32)b) << 16);
}
static __device__ __forceinline__ float sigmoidf(float x) {
  return __frcp_rn(1.0f + __expf(-x));
}
static __device__ __forceinline__ float fast_tanh(float x) {
  return 1.0f - 2.0f * __frcp_rn(__expf(2.0f * x) + 1.0f);
}
static __device__ __forceinline__ void async_copy16(const u16* g, const u16* l) {
  __builtin_amdgcn_global_load_lds(
      (const __attribute__((address_space(1))) u32*)g,
      (__attribute__((address_space(3))) u32*)l,
      16, 0, 0);
}

// ------- K0: weight cast + bias sum (first 2048 blocks) + feature bf16 ----
// Independent work merged into one dispatch; one fewer serialized launch.
__global__ __launch_bounds__(256) void feat_prep(
    const float* __restrict__ feat, const float* __restrict__ WgL,
    const float* __restrict__ WgR, u16* __restrict__ featb,
    float* __restrict__ glog,
    const float* __restrict__ Wih, const float* __restrict__ Whh,
    const float* __restrict__ bih, const float* __restrict__ bhh,
    u16* __restrict__ Wihb, u16* __restrict__ Whhb, float* __restrict__ bias) {
  int i = blockIdx.x * 256 + threadIdx.x;
  if (i < 1024 * 512) {
    Wihb[i] = f2bf(Wih[i]);
    if (i < 1024 * 256) Whhb[i] = f2bf(Whh[i]);
    if (i < 1024) bias[i] = bih[i] + bhh[i];
  }
  int wave = threadIdx.x >> 6, lane = threadIdx.x & 63;
  int n = blockIdx.x * 4 + wave;
  if (n >= N_MONO) return;
  float4 x = *(const float4*)(feat + (size_t)n * F + lane * 4);
  u32 lo = (u32)f2bf(x.x) | ((u32)f2bf(x.y) << 16);
  u32 hi = (u32)f2bf(x.z) | ((u32)f2bf(x.w) << 16);
  *(uint2*)(featb + (size_t)n * F + lane * 4) = make_uint2(lo, hi);
  float4 wl = *(const float4*)(WgL + lane * 4);
  float4 wr = *(const float4*)(WgR + lane * 4);
  float pl = x.x * wl.x + x.y * wl.y + x.z * wl.z + x.w * wl.w;
  float pr = x.x * wr.x + x.y * wr.y + x.z * wr.z + x.w * wr.w;
#pragma unroll
  for (int off = 32; off; off >>= 1) {
    pl += __shfl_xor(pl, off);
    pr += __shfl_xor(pr, off);
  }
  if (lane == 0) {
    glog[n * 2] = pl;
    glog[n * 2 + 1] = pr;
  }
}

// ---------------- K1: attention pulls -> cleav [N_CLEAV, 512] bf16 --------
// TWO cleavages per wave (R9 verified; x4 would halve occupancy -> no gain).
__global__ __launch_bounds__(256) void attn_pull2(
    const u16* __restrict__ featb, const float* __restrict__ glog,
    const int* __restrict__ lostS, const int* __restrict__ retS,
    u16* __restrict__ cleav) {
  int wave = threadIdx.x >> 6, lane = threadIdx.x & 63;
  int n0 = blockIdx.x * 8 + wave * 2;
  if (n0 >= N_CLEAV) return;
  int r[2][2][4];
#pragma unroll
  for (int c = 0; c < 2; ++c) {
    int4 rl = *(const int4*)(lostS + (n0 + c) * 4);
    int4 rr = *(const int4*)(retS + (n0 + c) * 4);
    r[c][0][0] = rl.x; r[c][0][1] = rl.y; r[c][0][2] = rl.z; r[c][0][3] = rl.w;
    r[c][1][0] = rr.x; r[c][1][1] = rr.y; r[c][1][2] = rr.z; r[c][1][3] = rr.w;
  }
  ushort4 x4[2][2][4];
  float lg[2][2][4];
#pragma unroll
  for (int c = 0; c < 2; ++c)
#pragma unroll
    for (int sg = 0; sg < 2; ++sg)
#pragma unroll
      for (int d = 0; d < 4; ++d) {
        x4[c][sg][d] = *(const ushort4*)(featb + (size_t)r[c][sg][d] * F + lane * 4);
        lg[c][sg][d] = glog[r[c][sg][d] * 2 + sg];
      }
#pragma unroll
  for (int c = 0; c < 2; ++c)
#pragma unroll
    for (int sg = 0; sg < 2; ++sg) {
      float l0 = lg[c][sg][0], l1 = lg[c][sg][1];
      float l2 = lg[c][sg][2], l3 = lg[c][sg][3];
      float mx = fmaxf(fmaxf(l0, l1), fmaxf(l2, l3));
      float e0 = __expf(l0 - mx), e1 = __expf(l1 - mx);
      float e2 = __expf(l2 - mx), e3 = __expf(l3 - mx);
      float inv = __frcp_rn(e0 + e1 + e2 + e3);
      float a[4] = {e0 * inv, e1 * inv, e2 * inv, e3 * inv};
      float acc[4] = {0.f, 0.f, 0.f, 0.f};
#pragma unroll
      for (int d = 0; d < 4; ++d) {
        const u16* xp = (const u16*)&x4[c][sg][d];
#pragma unroll
        for (int k = 0; k < 4; k++) acc[k] += a[d] * bf2f(xp[k]);
      }
      u32 lo = (u32)f2bf(acc[0]) | ((u32)f2bf(acc[1]) << 16);
      u32 hi = (u32)f2bf(acc[2]) | ((u32)f2bf(acc[3]) << 16);
      *(uint2*)(cleav + (size_t)(n0 + c) * 512 + sg * 256 + lane * 4) =
          make_uint2(lo, hi);
    }
}

// ---------------- GEMM-1: P = cleav @ Wih^T + bias (R9 best: dispatched) --
// BM=224 x 256 tile, BK=64, 8 waves, 4-phase double-buffered, vmcnt(4).
// 1792 blocks = 7/CU exact.  (R10 persistent variant was -2% -> reverted.)
__global__ __launch_bounds__(512, 2) void gemm224(
    const u16* __restrict__ A, const u16* __restrict__ Bw,
    u16* __restrict__ C, const float* __restrict__ bias,
    int nper, int mstrips_valid) {
  constexpr int K = 512, BM = 224;
  constexpr int AREG = BM * 64;
  constexpr int BSZ = AREG + 16384;
  constexpr int WMH = BM / 2;
  constexpr int IB = BM / 32;            // 7
  constexpr int IB_HI = IB - 4;          // 3
  __shared__ u16 sh[2][BSZ];
  const int flat = blockIdx.x;
  const int xcd = flat & 7;
  const int w = flat >> 3;
  const int mstrip = xcd * nper + (w >> 2);
  const int nstrip = w & 3;
  if (mstrip >= mstrips_valid) return;
  const int m0 = mstrip * BM;
  const int n0 = nstrip * 256;

  const int tid = threadIdx.x;
  const int lane = tid & 63;
  const int wave = tid >> 6;
  const int quad = lane >> 4;
  const int l16 = lane & 15;
  const int s7 = l16 & 7;
  const int wm2 = wave >> 2;
  const int wn4 = wave & 3;

  const int arow = (wm2 * WMH + l16) * 64;
  const int brow = AREG + (wn4 * 64 + l16) * 64;
  const int coff0 = (quad ^ s7) * 8;
  const int coff1 = ((4 + quad) ^ s7) * 8;

  int sr[4], sw[4], dwv[4];
#pragma unroll
  for (int r = 0; r < 4; r++) {
    int c = r * 512 + tid;
    sr[r] = c >> 3;
    sw[r] = ((c & 7) ^ ((c >> 3) & 7)) * 8;
    dwv[r] = (r * 512 + (tid & ~63)) * 8;
  }
  const u16* Abase = A + (size_t)m0 * K;
  const u16* Bbase = Bw + (size_t)n0 * K;

  auto stageA = [&](int buf, int kt, int h) {
#pragma unroll
    for (int rr = 0; rr < 2; rr++) {
      int r = 2 * h + rr;
      if (r * 512 + tid < BM * 8)
        async_copy16(Abase + (size_t)sr[r] * K + kt * 64 + sw[r], &sh[buf][dwv[r]]);
    }
  };
  auto stageB = [&](int buf, int kt, int h) {
#pragma unroll
    for (int rr = 0; rr < 2; rr++) {
      int r = 2 * h + rr;
      async_copy16(Bbase + (size_t)sr[r] * K + kt * 64 + sw[r], &sh[buf][AREG + dwv[r]]);
    }
  };

  f32x4 acc[IB][4];
#pragma unroll
  for (int i = 0; i < IB; i++)
#pragma unroll
    for (int j = 0; j < 4; j++) acc[i][j] = (f32x4){0.f, 0.f, 0.f, 0.f};

  constexpr int nK = K / 64;
  stageA(0, 0, 0); stageA(0, 0, 1); stageB(0, 0, 0); stageB(0, 0, 1);
  stageB(1, 1, 0); stageB(1, 1, 1);
  __builtin_amdgcn_s_waitcnt(0xF74);
  __builtin_amdgcn_s_barrier();

  bf16x8 a[4][2], b0[2][2], b1[2][2];
#pragma unroll
  for (int t = 0; t < nK; ++t) {
    const int bsel = t & 1;
    const u16* S = &sh[bsel][0];

#pragma unroll
    for (int i = 0; i < 4; i++) {
      a[i][0] = *(const bf16x8*)&S[arow + i * 1024 + coff0];
      a[i][1] = *(const bf16x8*)&S[arow + i * 1024 + coff1];
    }
#pragma unroll
    for (int j = 0; j < 2; j++) {
      b0[j][0] = *(const bf16x8*)&S[brow + j * 1024 + coff0];
      b0[j][1] = *(const bf16x8*)&S[brow + j * 1024 + coff1];
    }
    if (t + 1 < nK) stageA(bsel ^ 1, t + 1, 0);
    __builtin_amdgcn_s_waitcnt(0xC87F);
    __builtin_amdgcn_s_barrier();
    __builtin_amdgcn_s_waitcnt(0xC07F);
    __builtin_amdgcn_sched_barrier(0);
    __builtin_amdgcn_s_setprio(1);
#pragma unroll
    for (int i = 0; i < 4; i++)
#pragma unroll
      for (int j = 0; j < 2; j++) {
        acc[i][j] = __builtin_amdgcn_mfma_f32_16x16x32_bf16(a[i][0], b0[j][0], acc[i][j], 0, 0, 0);
        acc[i][j] = __builtin_amdgcn_mfma_f32_16x16x32_bf16(a[i][1], b0[j][1], acc[i][j], 0, 0, 0);
      }
    __builtin_amdgcn_s_setprio(0);
    __builtin_amdgcn_s_barrier();

#pragma unroll
    for (int j = 0; j < 2; j++) {
      b1[j][0] = *(const bf16x8*)&S[brow + (2 + j) * 1024 + coff0];
      b1[j][1] = *(const bf16x8*)&S[brow + (2 + j) * 1024 + coff1];
    }
    if (t + 1 < nK) stageA(bsel ^ 1, t + 1, 1);
    __builtin_amdgcn_s_barrier();
    __builtin_amdgcn_s_waitcnt(0xC07F);
    __builtin_amdgcn_sched_barrier(0);
    __builtin_amdgcn_s_setprio(1);
#pragma unroll
    for (int i = 0; i < 4; i++)
#pragma unroll
      for (int j = 0; j < 2; j++) {
        acc[i][2 + j] = __builtin_amdgcn_mfma_f32_16x16x32_bf16(a[i][0], b1[j][0], acc[i][2 + j], 0, 0, 0);
        acc[i][2 + j] = __builtin_amdgcn_mfma_f32_16x16x32_bf16(a[i][1], b1[j][1], acc[i][2 + j], 0, 0, 0);
      }
    __builtin_amdgcn_s_setprio(0);
    __builtin_amdgcn_s_barrier();

#pragma unroll
    for (int i = 0; i < IB_HI; i++) {
      a[i][0] = *(const bf16x8*)&S[arow + (4 + i) * 1024 + coff0];
      a[i][1] = *(const bf16x8*)&S[arow + (4 + i) * 1024 + coff1];
    }
    if (t + 2 < nK) stageB(bsel, t + 2, 0);
    __builtin_amdgcn_s_barrier();
    __builtin_amdgcn_s_waitcnt(0xC07F);
    __builtin_amdgcn_sched_barrier(0);
    __builtin_amdgcn_s_setprio(1);
#pragma unroll
    for (int i = 0; i < IB_HI; i++)
#pragma unroll
      for (int j = 0; j < 2; j++) {
        acc[4 + i][j] = __builtin_amdgcn_mfma_f32_16x16x32_bf16(a[i][0], b0[j][0], acc[4 + i][j], 0, 0, 0);
        acc[4 + i][j] = __builtin_amdgcn_mfma_f32_16x16x32_bf16(a[i][1], b0[j][1], acc[4 + i][j], 0, 0, 0);
      }
    __builtin_amdgcn_s_setprio(0);
    __builtin_amdgcn_s_barrier();

    if (t + 2 < nK) stageB(bsel, t + 2, 1);
    __builtin_amdgcn_s_barrier();
    __builtin_amdgcn_s_setprio(1);
#pragma unroll
    for (int i = 0; i < IB_HI; i++)
#pragma unroll
      for (int j = 0; j < 2; j++) {
        acc[4 + i][2 + j] = __builtin_amdgcn_mfma_f32_16x16x32_bf16(a[i][0], b1[j][0], acc[4 + i][2 + j], 0, 0, 0);
        acc[4 + i][2 + j] = __builtin_amdgcn_mfma_f32_16x16x32_bf16(a[i][1], b1[j][1], acc[4 + i][2 + j], 0, 0, 0);
      }
    __builtin_amdgcn_s_setprio(0);
    if (t + 2 < nK) __builtin_amdgcn_s_waitcnt(0xF74);
    else            __builtin_amdgcn_s_waitcnt(0xF70);
    __builtin_amdgcn_s_barrier();
  }

  float badd[4];
#pragma unroll
  for (int j = 0; j < 4; j++)
    badd[j] = bias[n0 + wn4 * 64 + j * 16 + l16];
#pragma unroll
  for (int i = 0; i < IB; i++) {
    const int mrow = m0 + wm2 * WMH + i * 16 + quad * 4;
#pragma unroll
    for (int j = 0; j < 4; j++) {
      const int n = n0 + wn4 * 64 + j * 16 + l16;
#pragma unroll
      for (int r = 0; r < 4; r++)
        C[(size_t)(mrow + r) * 1024 + n] = f2bf(acc[i][j][r] + badd[j]);
    }
  }
}

// ---------------- K3: LSTM step 1, FOUR fragments per wave ----------------
// ~60 VGPR keeps 8 waves/SIMD while doubling outstanding gathers (192->384
// per CU vs the x2 version).  80000 % 4 == 0 so each 4-group is entirely
// valid or entirely pad (wave-uniform branch).
__global__ __launch_bounds__(256) void lstm_step1(
    const u16* __restrict__ P, const int* __restrict__ join,
    u16* __restrict__ h1, u16* __restrict__ c1) {
  int wave = threadIdx.x >> 6, lane = threadIdx.x & 63;
  int m0 = blockIdx.x * 16 + wave * 4;
  if (m0 >= N_FRAG) {
    if (m0 < N_FRAG_PAD) {
#pragma unroll
      for (int c = 0; c < 4; ++c) {
        *(ushort4*)(h1 + (size_t)(m0 + c) * 256 + lane * 4) = make_ushort4(0, 0, 0, 0);
        *(ushort4*)(c1 + (size_t)(m0 + c) * 256 + lane * 4) = make_ushort4(0, 0, 0, 0);
      }
    }
    return;
  }
  int j0[4];
#pragma unroll
  for (int c = 0; c < 4; ++c) j0[c] = join[2 * (m0 + c)];
  ushort4 iv[4], gv[4], ov[4];
#pragma unroll
  for (int c = 0; c < 4; ++c) {
    const u16* row = P + (size_t)j0[c] * 1024 + lane * 4;
    iv[c] = *(const ushort4*)(row);
    gv[c] = *(const ushort4*)(row + 512);
    ov[c] = *(const ushort4*)(row + 768);
  }
#pragma unroll
  for (int c = 0; c < 4; ++c) {
    const u16* ivp = (const u16*)&iv[c];
    const u16* gvp = (const u16*)&gv[c];
    const u16* ovp = (const u16*)&ov[c];
    ushort4 h4, c4;
    u16* h4p = (u16*)&h4;
    u16* c4p = (u16*)&c4;
#pragma unroll
    for (int k = 0; k < 4; k++) {
      float cc = sigmoidf(bf2f(ivp[k])) * fast_tanh(bf2f(gvp[k]));
      float hv = sigmoidf(bf2f(ovp[k])) * fast_tanh(cc);
      h4p[k] = f2bf(hv);
      c4p[k] = f2bf(cc);
    }
    *(ushort4*)(h1 + (size_t)(m0 + c) * 256 + lane * 4) = h4;
    *(ushort4*)(c1 + (size_t)(m0 + c) * 256 + lane * 4) = c4;
  }
}

// ------- G2 fused: gates2 = h1 @ Whh^T (+P[j1], +c1) -> h2  ---------------
// 128x128 tile, BK=32, triple-buffered, 3 blocks/CU, XCD-colocated (R8).
__global__ __launch_bounds__(256, 3) void g2fuse(
    const u16* __restrict__ h1A, const u16* __restrict__ Whhb,
    const u16* __restrict__ P, const int* __restrict__ join,
    const u16* __restrict__ c1in, u16* __restrict__ h2s) {
  constexpr int K = 256;
  __shared__ u16 sh[6][128 * 32];   // A bufs 0-2, B bufs 3-5 (48 KiB)
  const int b = blockIdx.x;
  const int xcd = b & 7;
  const int k = b >> 3;             // 0..631
  const int nstrip = k & 7;
  const int mstrip = (k >> 3) * 8 + xcd;   // 0..631
  if (mstrip >= 626) return;
  const int m0 = mstrip * 128;

  const int tid = threadIdx.x;
  const int lane = tid & 63;
  const int wave = tid >> 6;
  const int quad = lane >> 4;
  const int l16 = lane & 15;
  const int wm = (wave & 1) * 64;
  const int wnq = wave >> 1;        // 0..1
  const int wn = wnq * 64;

  int srow[2], skoff[2], ldsoff[2], brow[2];
#pragma unroll
  for (int jj = 0; jj < 2; jj++) {
    int c = jj * 256 + tid;
    int row = c >> 2;
    srow[jj] = row;
    skoff[jj] = ((c & 3) ^ ((c >> 3) & 3)) * 8;
    ldsoff[jj] = (jj * 256 + (tid & ~63)) * 8;
    brow[jj] = ((row >> 4) & 3) * 256 + nstrip * 32 + ((row >> 6) << 4) + (row & 15);
  }
  const u16* Abase = h1A + (size_t)m0 * K;

  int jrow[8];
#pragma unroll
  for (int rd = 0; rd < 8; rd++) {
    int mm = m0 + rd * 16 + (tid >> 4);
    jrow[rd] = join[2 * (mm < N_FRAG ? mm : N_FRAG - 1) + 1];
  }

  auto stage = [&](int buf, int k0) {
#pragma unroll
    for (int jj = 0; jj < 2; jj++)
      async_copy16(Abase + (size_t)srow[jj] * K + k0 + skoff[jj], &sh[buf][ldsoff[jj]]);
#pragma unroll
    for (int jj = 0; jj < 2; jj++)
      async_copy16(Whhb + (size_t)brow[jj] * K + k0 + skoff[jj], &sh[3 + buf][ldsoff[jj]]);
  };

  f32x4 acc[4][4];
#pragma unroll
  for (int i = 0; i < 4; i++)
#pragma unroll
    for (int j = 0; j < 4; j++) acc[i][j] = (f32x4){0.f, 0.f, 0.f, 0.f};

  constexpr int nK = K / 32;        // 8
  stage(0, 0);
  stage(1, 32);
#pragma unroll
  for (int t = 0; t < nK; ++t) {
    if (t < nK - 1) __builtin_amdgcn_s_waitcnt(0xF74);  // vmcnt(4)
    else            __builtin_amdgcn_s_waitcnt(0xF70);  // vmcnt(0)
    __builtin_amdgcn_s_barrier();
    if (t + 2 < nK) stage((t + 2) % 3, (t + 2) * 32);
    const int buf = t % 3;
    bf16x8 af[4], bfr[4];
#pragma unroll
    for (int i = 0; i < 4; i++) {
      int m = wm + i * 16 + l16;
      int jp = quad ^ ((m >> 1) & 3);
      af[i] = *(const bf16x8*)&sh[buf][m * 32 + jp * 8];
    }
#pragma unroll
    for (int j = 0; j < 4; j++) {
      int n = wn + j * 16 + l16;
      int jp = quad ^ ((n >> 1) & 3);
      bfr[j] = *(const bf16x8*)&sh[3 + buf][n * 32 + jp * 8];
    }
#pragma unroll
    for (int i = 0; i < 4; i++)
#pragma unroll
      for (int j = 0; j < 4; j++)
        acc[i][j] = __builtin_amdgcn_mfma_f32_16x16x32_bf16(af[i], bfr[j], acc[i][j], 0, 0, 0);
  }

  // ---- fused LSTM step-2 epilogue ----
  __builtin_amdgcn_s_barrier();
  const int u_ = wnq * 16 + l16;
  u16 c1r[4][4];
#pragma unroll
  for (int i = 0; i < 4; i++)
#pragma unroll
    for (int r = 0; r < 4; r++) {
      int m = m0 + wm + i * 16 + quad * 4 + r;
      c1r[i][r] = c1in[(size_t)m * 256 + nstrip * 32 + u_];
    }
  u16* Pl = &sh[0][0];              // 32 KiB
  {
    const int g = (tid >> 2) & 3;
    const int chunk = tid & 3;
#pragma unroll
    for (int rd = 0; rd < 8; rd++) {
      const int mloc = rd * 16 + (tid >> 4);
      const int cphys = chunk ^ ((mloc >> 2) & 3);
      async_copy16(P + (size_t)jrow[rd] * 1024 + g * 256 + nstrip * 32 + cphys * 8,
                   &Pl[(size_t)(rd * 256 + (tid & ~63)) * 8]);
    }
  }
  __builtin_amdgcn_s_waitcnt(0xF70);
  __builtin_amdgcn_s_barrier();
  __builtin_amdgcn_sched_barrier(0);

#pragma unroll
  for (int i = 0; i < 4; i++) {
#pragma unroll
    for (int r = 0; r < 4; r++) {
      const int mloc = wm + i * 16 + quad * 4 + r;
      const int m = m0 + mloc;
      const int base = (mloc * 16 + ((u_ >> 3) ^ ((mloc >> 2) & 3))) * 8 + (u_ & 7);
      float gi = acc[i][0][r] + bf2f(Pl[base]);
      float gf = acc[i][1][r] + bf2f(Pl[base + 32]);
      float gg = acc[i][2][r] + bf2f(Pl[base + 64]);
      float go = acc[i][3][r] + bf2f(Pl[base + 96]);
      float c1v = bf2f(c1r[i][r]);
      float cv = sigmoidf(gf) * c1v + sigmoidf(gi) * fast_tanh(gg);
      float hv = sigmoidf(go) * fast_tanh(cv);
      h2s[(size_t)m * 256 + nstrip * 32 + u_] = f2bf(hv);
    }
  }
}

// ------- K5: attention over {h1,h2} + output head, TWO frags per wave -----
__global__ __launch_bounds__(256) void lstm_attn_out(
    const u16* __restrict__ h1, const u16* __restrict__ h2s,
    const float* __restrict__ Wg, const float* __restrict__ Wout,
    const float* __restrict__ bout, float* __restrict__ frag_out) {
  int wave = threadIdx.x >> 6, lane = threadIdx.x & 63;
  int m0 = blockIdx.x * 8 + wave * 2;
  if (m0 >= N_FRAG) return;
  const int nf = (m0 + 1 < N_FRAG) ? 2 : 1;
  ushort4 h1v[2], h2v[2];
#pragma unroll
  for (int c = 0; c < 2; ++c) {
    int m = m0 + (c < nf ? c : 0);
    h1v[c] = *(const ushort4*)(h1 + (size_t)m * 256 + lane * 4);
    h2v[c] = *(const ushort4*)(h2s + (size_t)m * 256 + lane * 4);
  }
  float4 wg = *(const float4*)(Wg + lane * 4);
  const float* wgp = (const float*)&wg;

  float p1[2], p2[2];
#pragma unroll
  for (int c = 0; c < 2; ++c) {
    const u16* h1p = (const u16*)&h1v[c];
    const u16* h2p = (const u16*)&h2v[c];
    float a = 0.f, b = 0.f;
#pragma unroll
    for (int k = 0; k < 4; k++) {
      a += bf2f(h1p[k]) * wgp[k];
      b += bf2f(h2p[k]) * wgp[k];
    }
    p1[c] = a; p2[c] = b;
  }
#pragma unroll
  for (int off = 32; off; off >>= 1)
#pragma unroll
    for (int c = 0; c < 2; ++c) {
      p1[c] += __shfl_xor(p1[c], off);
      p2[c] += __shfl_xor(p2[c], off);
    }

  float acc[2][8];
#pragma unroll
  for (int c = 0; c < 2; ++c) {
    float mx = fmaxf(p1[c], p2[c]);
    float e1 = __expf(p1[c] - mx), e2 = __expf(p2[c] - mx);
    float inv = __frcp_rn(e1 + e2);
    float a1 = e1 * inv, a2 = e2 * inv;
    const u16* h1p = (const u16*)&h1v[c];
    const u16* h2p = (const u16*)&h2v[c];
#pragma unroll
    for (int t = 0; t < 8; t++) acc[c][t] = 0.f;
#pragma unroll
    for (int k = 0; k < 4; k++) {
      float frag = a1 * bf2f(h1p[k]) + a2 * bf2f(h2p[k]);
      int h = lane * 4 + k;
      float4 w0 = *(const float4*)(Wout + h * 8);
      float4 w1 = *(const float4*)(Wout + h * 8 + 4);
      acc[c][0] += frag * w0.x; acc[c][1] += frag * w0.y;
      acc[c][2] += frag * w0.z; acc[c][3] += frag * w0.w;
      acc[c][4] += frag * w1.x; acc[c][5] += frag * w1.y;
      acc[c][6] += frag * w1.z; acc[c][7] += frag * w1.w;
    }
  }
#pragma unroll
  for (int off = 32; off; off >>= 1)
#pragma unroll
    for (int c = 0; c < 2; ++c)
#pragma unroll
      for (int t = 0; t < 8; t++) acc[c][t] += __shfl_xor(acc[c][t], off);
  if (lane == 0) {
#pragma unroll
    for (int c = 0; c < 2; ++c) {
      if (c >= nf) break;
      float4 o0, o1;
      o0.x = fmaxf(acc[c][0] + bout[0], 0.f);
      o0.y = fmaxf(acc[c][1] + bout[1], 0.f);
      o0.z = fmaxf(acc[c][2] + bout[2], 0.f);
      o0.w = fmaxf(acc[c][3] + bout[3], 0.f);
      o1.x = fmaxf(acc[c][4] + bout[4], 0.f);
      o1.y = fmaxf(acc[c][5] + bout[5], 0.f);
      o1.z = fmaxf(acc[c][6] + bout[6], 0.f);
      o1.w = fmaxf(acc[c][7] + bout[7], 0.f);
      *(float4*)(frag_out + (size_t)(m0 + c) * 8) = o0;
      *(float4*)(frag_out + (size_t)(m0 + c) * 8 + 4) = o1;
    }
  }
}

// ---------------- K6: combine scatter-sum ---------------------------------
__global__ __launch_bounds__(256) void scatter_sum(
    const float* __restrict__ frag_out, const int* __restrict__ comb,
    float* __restrict__ out) {
  int tid = blockIdx.x * 256 + threadIdx.x;
  if (tid >= N_OUT * 8) return;
  int n = tid >> 3, t = tid & 7;
  float s = 0.f;
#pragma unroll
  for (int d = 0; d < 4; d++) {
    int f = comb[n * 4 + d];
    s += frag_out[(size_t)f * 8 + t];
  }
  out[tid] = s;
}

extern "C" void kernel_launch(void* const* d_in, const int* in_sizes, int n_in,
                              void* d_out, int out_size, void* d_ws, size_t ws_size,
                              hipStream_t stream) {
  const float* feature = (const float*)d_in[0];
  const float* WgL = (const float*)d_in[1];
  const float* WgR = (const float*)d_in[2];
  const float* Wih = (const float*)d_in[3];
  const float* Whh = (const float*)d_in[4];
  const float* bih = (const float*)d_in[5];
  const float* bhh = (const float*)d_in[6];
  const float* Wgf = (const float*)d_in[7];
  const float* Wout = (const float*)d_in[8];
  const float* bout = (const float*)d_in[9];
  const int* lostS = (const int*)d_in[10];
  const int* retS = (const int*)d_in[11];
  const int* joinS = (const int*)d_in[12];
  const int* combS = (const int*)d_in[13];
  float* out = (float*)d_out;

  char* ws = (char*)d_ws;
  size_t off = 0;
  auto alloc = [&](size_t bytes) -> char* {
    char* p = ws + off;
    off = (off + bytes + 255) & ~(size_t)255;
    return p;
  };
  u16* Wihb = (u16*)alloc((size_t)1024 * 512 * 2);
  u16* Whhb = (u16*)alloc((size_t)1024 * 256 * 2);
  float* bias = (float*)alloc(1024 * 4);
  u16* P = (u16*)alloc((size_t)M_CLEAV_PAD * 1024 * 2);
  u16* h1 = (u16*)alloc((size_t)N_FRAG_PAD * 256 * 2);
  u16* c1 = (u16*)alloc((size_t)N_FRAG_PAD * 256 * 2);
  u16* h2s = (u16*)alloc((size_t)N_FRAG_PAD * 256 * 2);
  float* frag_out = (float*)alloc((size_t)N_FRAG * 8 * 4);
  u16* cleav = (u16*)alloc((size_t)M_CLEAV_PAD * 512 * 2);
  // featb (76.8 MB) + glog (1.2 MB) alias the P region: dead once
  // attn_pull2 completes, before GEMM-1 writes P (stream-ordered).
  u16* featb = P;
  float* glog = (float*)(P + (size_t)N_MONO * F);

  feat_prep<<<(N_MONO + 3) / 4, 256, 0, stream>>>(
      feature, WgL, WgR, featb, glog, Wih, Whh, bih, bhh, Wihb, Whhb, bias);
  attn_pull2<<<N_CLEAV / 8, 256, 0, stream>>>(featb, glog, lostS, retS, cleav);
  // GEMM-1: M=100352 = 448*224 strips, 56/XCD, 1792 blocks = 7/CU exact
  gemm224<<<1792, 512, 0, stream>>>(cleav, Wihb, P, bias, 56, 448);
  lstm_step1<<<N_FRAG_PAD / 16, 256, 0, stream>>>(P, joinS, h1, c1);
  // G2 fused: 632 virtual mstrips (79/XCD) x 8 nstrips, XCD-colocated
  g2fuse<<<632 * 8, 256, 0, stream>>>(h1, Whhb, P, joinS, c1, h2s);
  lstm_attn_out<<<(N_FRAG + 7) / 8, 256, 0, stream>>>(
      h1, h2s, Wgf, Wout, bout, frag_out);
  scatter_sum<<<(N_OUT * 8 + 255) / 256, 256, 0, stream>>>(frag_out, combS, out);
}